// Round 1
// baseline (475.072 us; speedup 1.0000x reference)
//
#include <hip/hip_runtime.h>
#include <hip/hip_bf16.h>
#include <stdint.h>
#include <math.h>

#define NHEAD 16
#define DK 64
#define SEQ 2048
#define BATCH 2
#define DMODEL 1024

typedef __attribute__((ext_vector_type(8))) short short8_t;
typedef __attribute__((ext_vector_type(4))) float f32x4;

#define MFMA(a, b, c) __builtin_amdgcn_mfma_f32_16x16x32_bf16(a, b, c, 0, 0, 0)

__device__ __forceinline__ unsigned short f2bf(float f) {
    unsigned int u = __float_as_uint(f);
    u += 0x7fffu + ((u >> 16) & 1u);   // round-to-nearest-even
    return (unsigned short)(u >> 16);
}
__device__ __forceinline__ float bf2f(unsigned short h) {
    return __uint_as_float(((unsigned int)h) << 16);
}

// ---------------------------------------------------------------------------
// Projection: dst[b,h,l,d] = (X @ W^T + bias), stored as bf16 hi/lo planes.
// X: [B*L, 1024] f32 row-major.  W: [1024, 1024] f32 row-major ([out,in]).
// NT GEMM: C[m,o] = sum_k X[m,k] * W[o,k].
// Block: 256 thr = 4 waves; tile 64x64, BK=32; wave w owns rows [w*16, w*16+16).
// Split precision: 3 MFMA products (hi*hi + hi*lo + lo*hi).
// ---------------------------------------------------------------------------
__global__ __launch_bounds__(256) void proj_split_kernel(
    const float* __restrict__ X, const float* __restrict__ W,
    const float* __restrict__ bias,
    unsigned short* __restrict__ dst_hi, unsigned short* __restrict__ dst_lo)
{
    __shared__ unsigned short Ahi[64][40];
    __shared__ unsigned short Alo[64][40];
    __shared__ unsigned short Bhi[64][40];
    __shared__ unsigned short Blo[64][40];

    const int tid = threadIdx.x;
    const int lane = tid & 63;
    const int wv = tid >> 6;
    const int fr = lane & 15;
    const int fg = lane >> 4;
    const int m0 = blockIdx.y * 64;
    const int n0 = blockIdx.x * 64;

    const int srow = tid >> 2;          // 0..63
    const int scol = (tid & 3) * 8;     // 0,8,16,24

    f32x4 acc[4];
    const f32x4 fzero = {0.f, 0.f, 0.f, 0.f};
#pragma unroll
    for (int n = 0; n < 4; n++) acc[n] = fzero;

    for (int k0 = 0; k0 < DMODEL; k0 += 32) {
        __syncthreads();
        {
            const float* pa = X + (size_t)(m0 + srow) * DMODEL + k0 + scol;
            const float* pb = W + (size_t)(n0 + srow) * DMODEL + k0 + scol;
            f32x4 a0 = *(const f32x4*)pa;
            f32x4 a1 = *(const f32x4*)(pa + 4);
            f32x4 b0 = *(const f32x4*)pb;
            f32x4 b1 = *(const f32x4*)(pb + 4);
            union { short8_t v; unsigned short u[8]; } ah, al, bh, bl;
#pragma unroll
            for (int j = 0; j < 4; j++) {
                float fa = a0[j]; unsigned short h = f2bf(fa);
                ah.u[j] = h; al.u[j] = f2bf(fa - bf2f(h));
                fa = a1[j]; h = f2bf(fa);
                ah.u[4 + j] = h; al.u[4 + j] = f2bf(fa - bf2f(h));
                float fb = b0[j]; h = f2bf(fb);
                bh.u[j] = h; bl.u[j] = f2bf(fb - bf2f(h));
                fb = b1[j]; h = f2bf(fb);
                bh.u[4 + j] = h; bl.u[4 + j] = f2bf(fb - bf2f(h));
            }
            *(short8_t*)&Ahi[srow][scol] = ah.v;
            *(short8_t*)&Alo[srow][scol] = al.v;
            *(short8_t*)&Bhi[srow][scol] = bh.v;
            *(short8_t*)&Blo[srow][scol] = bl.v;
        }
        __syncthreads();

        short8_t a_hi = *(const short8_t*)&Ahi[wv * 16 + fr][fg * 8];
        short8_t a_lo = *(const short8_t*)&Alo[wv * 16 + fr][fg * 8];
#pragma unroll
        for (int n = 0; n < 4; n++) {
            short8_t b_hi = *(const short8_t*)&Bhi[n * 16 + fr][fg * 8];
            short8_t b_lo = *(const short8_t*)&Blo[n * 16 + fr][fg * 8];
            acc[n] = MFMA(a_hi, b_hi, acc[n]);
            acc[n] = MFMA(a_hi, b_lo, acc[n]);
            acc[n] = MFMA(a_lo, b_hi, acc[n]);
        }
    }

    // Epilogue: C row = m0 + wv*16 + fg*4 + r ; col = n0 + n*16 + fr
#pragma unroll
    for (int n = 0; n < 4; n++) {
#pragma unroll
        for (int r = 0; r < 4; r++) {
            int gm = m0 + wv * 16 + fg * 4 + r;     // 0..4095 (b*2048 + l)
            int go = n0 + n * 16 + fr;              // 0..1023 (h*64 + d)
            float v = acc[n][r] + bias[go];
            int bb = gm >> 11;
            int ll = gm & (SEQ - 1);
            int hh = go >> 6;
            int dd = go & (DK - 1);
            size_t idx = (((size_t)(bb * NHEAD + hh) * SEQ) + ll) * DK + dd;
            unsigned short h = f2bf(v);
            dst_hi[idx] = h;
            dst_lo[idx] = f2bf(v - bf2f(h));
        }
    }
}

// ---------------------------------------------------------------------------
// LSH flash attention. Grid: (q-block 32, b*h 32). Block: 4 waves.
// Wave w handles q-rows [q0 + w*16, +16). KV tiles of 32 keys.
// QK^T: 3-product split. PV: 3-product split (P hi/lo via LDS, V hi/lo
// staged transposed).  Online softmax in f32.
// ---------------------------------------------------------------------------
__global__ __launch_bounds__(256) void lsh_attn_kernel(
    const unsigned short* __restrict__ Qhi, const unsigned short* __restrict__ Qlo,
    const unsigned short* __restrict__ Khi, const unsigned short* __restrict__ Klo,
    const unsigned short* __restrict__ Vhi, const unsigned short* __restrict__ Vlo,
    const int* __restrict__ hash_q, const int* __restrict__ hash_k,
    float* __restrict__ out)
{
    __shared__ unsigned short KshH[32][72];
    __shared__ unsigned short KshL[32][72];
    __shared__ unsigned short VtH[64][40];   // transposed: [d][key]
    __shared__ unsigned short VtL[64][40];
    __shared__ unsigned short PlH[4][16][40];
    __shared__ unsigned short PlL[4][16][40];
    __shared__ int hks[32];
    __shared__ int hqs[64];

    const int tid = threadIdx.x;
    const int lane = tid & 63;
    const int wv = tid >> 6;
    const int fr = lane & 15;
    const int fg = lane >> 4;
    const int bh = blockIdx.y;          // b*16 + h
    const int q0 = blockIdx.x * 64;

    const size_t base = (size_t)bh * SEQ * DK;

    // Q fragments in registers (rows q0 + wv*16 + fr)
    short8_t q_hi[2], q_lo[2];
    {
        const size_t ro = base + (size_t)(q0 + wv * 16 + fr) * DK;
#pragma unroll
        for (int ks = 0; ks < 2; ks++) {
            q_hi[ks] = *(const short8_t*)(Qhi + ro + ks * 32 + fg * 8);
            q_lo[ks] = *(const short8_t*)(Qlo + ro + ks * 32 + fg * 8);
        }
    }
    if (tid < 64) hqs[tid] = hash_q[(size_t)bh * SEQ + q0 + tid];

    float m_r[4], l_r[4];
    f32x4 o_acc[4];
    const f32x4 fzero = {0.f, 0.f, 0.f, 0.f};
#pragma unroll
    for (int r = 0; r < 4; r++) { m_r[r] = -INFINITY; l_r[r] = 0.f; }
#pragma unroll
    for (int t = 0; t < 4; t++) o_acc[t] = fzero;

    const int krow = tid >> 3;          // 0..31
    const int kcol = (tid & 7) * 8;     // 0..56

    for (int k0 = 0; k0 < SEQ; k0 += 32) {
        __syncthreads();   // previous tile fully consumed (also orders hqs)
        {
            const size_t off = base + (size_t)(k0 + krow) * DK + kcol;
            *(short8_t*)&KshH[krow][kcol] = *(const short8_t*)(Khi + off);
            *(short8_t*)&KshL[krow][kcol] = *(const short8_t*)(Klo + off);
            union { short8_t v; unsigned short u[8]; } vh, vl;
            vh.v = *(const short8_t*)(Vhi + off);
            vl.v = *(const short8_t*)(Vlo + off);
#pragma unroll
            for (int j = 0; j < 8; j++) {
                VtH[kcol + j][krow] = vh.u[j];
                VtL[kcol + j][krow] = vl.u[j];
            }
            if (tid < 32) hks[tid] = hash_k[(size_t)bh * SEQ + k0 + tid];
        }
        __syncthreads();

        // S = Q K^T (two 16-key column tiles), split precision
        f32x4 s0 = fzero, s1 = fzero;
#pragma unroll
        for (int ks = 0; ks < 2; ks++) {
            short8_t kh0 = *(const short8_t*)&KshH[fr][ks * 32 + fg * 8];
            short8_t kl0 = *(const short8_t*)&KshL[fr][ks * 32 + fg * 8];
            short8_t kh1 = *(const short8_t*)&KshH[16 + fr][ks * 32 + fg * 8];
            short8_t kl1 = *(const short8_t*)&KshL[16 + fr][ks * 32 + fg * 8];
            s0 = MFMA(q_hi[ks], kh0, s0);
            s0 = MFMA(q_hi[ks], kl0, s0);
            s0 = MFMA(q_lo[ks], kh0, s0);
            s1 = MFMA(q_hi[ks], kh1, s1);
            s1 = MFMA(q_hi[ks], kl1, s1);
            s1 = MFMA(q_lo[ks], kh1, s1);
        }

        // mask + scale; C layout: row = fg*4+r, col = fr (tile0) / 16+fr (tile1)
        const int hk0 = hks[fr], hk1 = hks[16 + fr];
        float pmax[4];
#pragma unroll
        for (int r = 0; r < 4; r++) {
            const int hq = hqs[wv * 16 + fg * 4 + r];
            float v0 = s0[r] * 0.125f + ((hq == hk0) ? 0.f : -1e9f);
            float v1 = s1[r] * 0.125f + ((hq == hk1) ? 0.f : -1e9f);
            s0[r] = v0; s1[r] = v1;
            pmax[r] = fmaxf(v0, v1);
        }
#pragma unroll
        for (int d = 1; d < 16; d <<= 1) {
#pragma unroll
            for (int r = 0; r < 4; r++)
                pmax[r] = fmaxf(pmax[r], __shfl_xor(pmax[r], d, 64));
        }

        float psum[4];
#pragma unroll
        for (int r = 0; r < 4; r++) {
            float mn = fmaxf(m_r[r], pmax[r]);
            float sc = __expf(m_r[r] - mn);   // exp(-inf)=0 on first tile
            m_r[r] = mn;
            l_r[r] *= sc;
#pragma unroll
            for (int t = 0; t < 4; t++) o_acc[t][r] *= sc;
            float p0 = __expf(s0[r] - mn);
            float p1 = __expf(s1[r] - mn);
            s0[r] = p0; s1[r] = p1;
            psum[r] = p0 + p1;
        }
#pragma unroll
        for (int d = 1; d < 16; d <<= 1) {
#pragma unroll
            for (int r = 0; r < 4; r++)
                psum[r] += __shfl_xor(psum[r], d, 64);
        }
#pragma unroll
        for (int r = 0; r < 4; r++) l_r[r] += psum[r];

        // P -> LDS as hi/lo bf16 (wave-private region)
#pragma unroll
        for (int r = 0; r < 4; r++) {
            unsigned short h0 = f2bf(s0[r]);
            unsigned short h1 = f2bf(s1[r]);
            PlH[wv][fg * 4 + r][fr] = h0;
            PlL[wv][fg * 4 + r][fr] = f2bf(s0[r] - bf2f(h0));
            PlH[wv][fg * 4 + r][16 + fr] = h1;
            PlL[wv][fg * 4 + r][16 + fr] = f2bf(s1[r] - bf2f(h1));
        }
        __syncthreads();

        // O += P V  (A = P [16 x 32keys], B = V^T rows)
        short8_t p_hi = *(const short8_t*)&PlH[wv][fr][fg * 8];
        short8_t p_lo = *(const short8_t*)&PlL[wv][fr][fg * 8];
#pragma unroll
        for (int dt = 0; dt < 4; dt++) {
            short8_t v_hi = *(const short8_t*)&VtH[dt * 16 + fr][fg * 8];
            short8_t v_lo = *(const short8_t*)&VtL[dt * 16 + fr][fg * 8];
            o_acc[dt] = MFMA(p_hi, v_hi, o_acc[dt]);
            o_acc[dt] = MFMA(p_hi, v_lo, o_acc[dt]);
            o_acc[dt] = MFMA(p_lo, v_hi, o_acc[dt]);
        }
    }

    // Epilogue: out[b, q, h*64 + d], f32
    const int b = bh >> 4, h = bh & 15;
#pragma unroll
    for (int dt = 0; dt < 4; dt++) {
#pragma unroll
        for (int r = 0; r < 4; r++) {
            int qrow = q0 + wv * 16 + fg * 4 + r;
            int dcol = dt * 16 + fr;
            float val = o_acc[dt][r] / l_r[r];
            out[((size_t)(b * SEQ + qrow)) * DMODEL + h * DK + dcol] = val;
        }
    }
}

// ---------------------------------------------------------------------------

extern "C" void kernel_launch(void* const* d_in, const int* in_sizes, int n_in,
                              void* d_out, int out_size, void* d_ws, size_t ws_size,
                              hipStream_t stream)
{
    const float* query = (const float*)d_in[0];
    const float* key   = (const float*)d_in[1];
    const float* value = (const float*)d_in[2];
    const int* hash_q  = (const int*)d_in[3];
    const int* hash_k  = (const int*)d_in[4];
    const float* Wq    = (const float*)d_in[5];
    const float* bq    = (const float*)d_in[6];
    const float* Wk    = (const float*)d_in[7];
    const float* bk    = (const float*)d_in[8];
    const float* Wv    = (const float*)d_in[9];
    const float* bv    = (const float*)d_in[10];
    float* out = (float*)d_out;

    const size_t plane = (size_t)BATCH * NHEAD * SEQ * DK;   // 4,194,304 elems
    unsigned short* ws = (unsigned short*)d_ws;               // need 6 planes = 48 MB
    unsigned short* pQhi = ws;
    unsigned short* pQlo = ws + plane;
    unsigned short* pKhi = ws + 2 * plane;
    unsigned short* pKlo = ws + 3 * plane;
    unsigned short* pVhi = ws + 4 * plane;
    unsigned short* pVlo = ws + 5 * plane;

    dim3 grid(DMODEL / 64, (BATCH * SEQ) / 64);   // (16, 64)
    proj_split_kernel<<<grid, 256, 0, stream>>>(query, Wq, bq, pQhi, pQlo);
    proj_split_kernel<<<grid, 256, 0, stream>>>(key,   Wk, bk, pKhi, pKlo);
    proj_split_kernel<<<grid, 256, 0, stream>>>(value, Wv, bv, pVhi, pVlo);

    dim3 agrid(SEQ / 64, BATCH * NHEAD);          // (32, 32)
    lsh_attn_kernel<<<agrid, 256, 0, stream>>>(pQhi, pQlo, pKhi, pKlo, pVhi, pVlo,
                                               hash_q, hash_k, out);
}

// Round 2
// 377.527 us; speedup vs baseline: 1.2584x; 1.2584x over previous
//
#include <hip/hip_runtime.h>
#include <hip/hip_bf16.h>
#include <stdint.h>
#include <math.h>

#define NHEAD 16
#define DK 64
#define SEQ 2048
#define BATCH 2
#define DMODEL 1024

typedef __attribute__((ext_vector_type(8))) short short8_t;
typedef __attribute__((ext_vector_type(4))) float f32x4;

#define MFMA(a, b, c) __builtin_amdgcn_mfma_f32_16x16x32_bf16(a, b, c, 0, 0, 0)

__device__ __forceinline__ unsigned short f2bf(float f) {
    unsigned int u = __float_as_uint(f);
    u += 0x7fffu + ((u >> 16) & 1u);   // round-to-nearest-even
    return (unsigned short)(u >> 16);
}
__device__ __forceinline__ float bf2f(unsigned short h) {
    return __uint_as_float(((unsigned int)h) << 16);
}

// ---------------------------------------------------------------------------
// proj_nt: dst[b,h,l,d] = (X @ W^T + bias) as bf16 (hi, optionally lo plane).
// Internal math: 3-product split bf16 MFMA (accurate to ~2^-18 relative).
// ---------------------------------------------------------------------------
template <bool WRITE_LO>
__global__ __launch_bounds__(256) void proj_nt_kernel(
    const float* __restrict__ X, const float* __restrict__ W,
    const float* __restrict__ bias,
    unsigned short* __restrict__ dst_hi, unsigned short* __restrict__ dst_lo)
{
    __shared__ unsigned short Ahi[64][40];
    __shared__ unsigned short Alo[64][40];
    __shared__ unsigned short Bhi[64][40];
    __shared__ unsigned short Blo[64][40];

    const int tid = threadIdx.x;
    const int lane = tid & 63;
    const int wv = tid >> 6;
    const int fr = lane & 15;
    const int fg = lane >> 4;
    const int m0 = blockIdx.y * 64;
    const int n0 = blockIdx.x * 64;

    const int srow = tid >> 2;          // 0..63
    const int scol = (tid & 3) * 8;     // 0,8,16,24

    f32x4 acc[4];
    const f32x4 fzero = {0.f, 0.f, 0.f, 0.f};
#pragma unroll
    for (int n = 0; n < 4; n++) acc[n] = fzero;

    for (int k0 = 0; k0 < DMODEL; k0 += 32) {
        __syncthreads();
        {
            const float* pa = X + (size_t)(m0 + srow) * DMODEL + k0 + scol;
            const float* pb = W + (size_t)(n0 + srow) * DMODEL + k0 + scol;
            f32x4 a0 = *(const f32x4*)pa;
            f32x4 a1 = *(const f32x4*)(pa + 4);
            f32x4 b0 = *(const f32x4*)pb;
            f32x4 b1 = *(const f32x4*)(pb + 4);
            union { short8_t v; unsigned short u[8]; } ah, al, bh, bl;
#pragma unroll
            for (int j = 0; j < 4; j++) {
                float fa = a0[j]; unsigned short h = f2bf(fa);
                ah.u[j] = h; al.u[j] = f2bf(fa - bf2f(h));
                fa = a1[j]; h = f2bf(fa);
                ah.u[4 + j] = h; al.u[4 + j] = f2bf(fa - bf2f(h));
                float fb = b0[j]; h = f2bf(fb);
                bh.u[j] = h; bl.u[j] = f2bf(fb - bf2f(h));
                fb = b1[j]; h = f2bf(fb);
                bh.u[4 + j] = h; bl.u[4 + j] = f2bf(fb - bf2f(h));
            }
            *(short8_t*)&Ahi[srow][scol] = ah.v;
            *(short8_t*)&Alo[srow][scol] = al.v;
            *(short8_t*)&Bhi[srow][scol] = bh.v;
            *(short8_t*)&Blo[srow][scol] = bl.v;
        }
        __syncthreads();

        short8_t a_hi = *(const short8_t*)&Ahi[wv * 16 + fr][fg * 8];
        short8_t a_lo = *(const short8_t*)&Alo[wv * 16 + fr][fg * 8];
#pragma unroll
        for (int n = 0; n < 4; n++) {
            short8_t b_hi = *(const short8_t*)&Bhi[n * 16 + fr][fg * 8];
            short8_t b_lo = *(const short8_t*)&Blo[n * 16 + fr][fg * 8];
            acc[n] = MFMA(a_hi, b_hi, acc[n]);
            acc[n] = MFMA(a_hi, b_lo, acc[n]);
            acc[n] = MFMA(a_lo, b_hi, acc[n]);
        }
    }

    // C row = m0 + wv*16 + fg*4 + r ; col = n0 + n*16 + fr
#pragma unroll
    for (int n = 0; n < 4; n++) {
#pragma unroll
        for (int r = 0; r < 4; r++) {
            int gm = m0 + wv * 16 + fg * 4 + r;     // b*2048 + l
            int go = n0 + n * 16 + fr;              // h*64 + d
            float v = acc[n][r] + bias[go];
            int bb = gm >> 11;
            int ll = gm & (SEQ - 1);
            int hh = go >> 6;
            int dd = go & (DK - 1);
            size_t idx = (((size_t)(bb * NHEAD + hh) * SEQ) + ll) * DK + dd;
            unsigned short h = f2bf(v);
            dst_hi[idx] = h;
            if constexpr (WRITE_LO) dst_lo[idx] = f2bf(v - bf2f(h));
        }
    }
}

// ---------------------------------------------------------------------------
// proj_tn: dstT[b,h,d,l] = (X @ W^T + bias)^T as bf16 hi.
// Swapped operands: A = W rows (out-dims = C rows), B = X rows (m = C cols)
// -> C comes out transposed with coalesced stores along l.
// ---------------------------------------------------------------------------
__global__ __launch_bounds__(256) void proj_tn_kernel(
    const float* __restrict__ X, const float* __restrict__ W,
    const float* __restrict__ bias, unsigned short* __restrict__ dstT)
{
    __shared__ unsigned short Ahi[64][40];
    __shared__ unsigned short Alo[64][40];
    __shared__ unsigned short Bhi[64][40];
    __shared__ unsigned short Blo[64][40];

    const int tid = threadIdx.x;
    const int lane = tid & 63;
    const int wv = tid >> 6;
    const int fr = lane & 15;
    const int fg = lane >> 4;
    const int m0 = blockIdx.x * 64;     // rows of X (b*l)
    const int n0 = blockIdx.y * 64;     // out-dims

    const int srow = tid >> 2;
    const int scol = (tid & 3) * 8;

    f32x4 acc[4];
    const f32x4 fzero = {0.f, 0.f, 0.f, 0.f};
#pragma unroll
    for (int j = 0; j < 4; j++) acc[j] = fzero;

    for (int k0 = 0; k0 < DMODEL; k0 += 32) {
        __syncthreads();
        {
            const float* pa = W + (size_t)(n0 + srow) * DMODEL + k0 + scol;  // A = W
            const float* pb = X + (size_t)(m0 + srow) * DMODEL + k0 + scol;  // B = X
            f32x4 a0 = *(const f32x4*)pa;
            f32x4 a1 = *(const f32x4*)(pa + 4);
            f32x4 b0 = *(const f32x4*)pb;
            f32x4 b1 = *(const f32x4*)(pb + 4);
            union { short8_t v; unsigned short u[8]; } ah, al, bh, bl;
#pragma unroll
            for (int j = 0; j < 4; j++) {
                float fa = a0[j]; unsigned short h = f2bf(fa);
                ah.u[j] = h; al.u[j] = f2bf(fa - bf2f(h));
                fa = a1[j]; h = f2bf(fa);
                ah.u[4 + j] = h; al.u[4 + j] = f2bf(fa - bf2f(h));
                float fb = b0[j]; h = f2bf(fb);
                bh.u[j] = h; bl.u[j] = f2bf(fb - bf2f(h));
                fb = b1[j]; h = f2bf(fb);
                bh.u[4 + j] = h; bl.u[4 + j] = f2bf(fb - bf2f(h));
            }
            *(short8_t*)&Ahi[srow][scol] = ah.v;
            *(short8_t*)&Alo[srow][scol] = al.v;
            *(short8_t*)&Bhi[srow][scol] = bh.v;
            *(short8_t*)&Blo[srow][scol] = bl.v;
        }
        __syncthreads();

        short8_t a_hi = *(const short8_t*)&Ahi[wv * 16 + fr][fg * 8];
        short8_t a_lo = *(const short8_t*)&Alo[wv * 16 + fr][fg * 8];
#pragma unroll
        for (int j = 0; j < 4; j++) {
            short8_t b_hi = *(const short8_t*)&Bhi[j * 16 + fr][fg * 8];
            short8_t b_lo = *(const short8_t*)&Blo[j * 16 + fr][fg * 8];
            acc[j] = MFMA(a_hi, b_hi, acc[j]);
            acc[j] = MFMA(a_hi, b_lo, acc[j]);
            acc[j] = MFMA(a_lo, b_hi, acc[j]);
        }
    }

    // C row = out-dim = n0 + wv*16 + fg*4 + r ; col = m = m0 + j*16 + fr
#pragma unroll
    for (int j = 0; j < 4; j++) {
#pragma unroll
        for (int r = 0; r < 4; r++) {
            int od = n0 + wv * 16 + fg * 4 + r;     // h*64 + d
            int gm = m0 + j * 16 + fr;              // b*2048 + l
            float v = acc[j][r] + bias[od];
            int bb = gm >> 11;
            int ll = gm & (SEQ - 1);
            int hh = od >> 6;
            int dd = od & (DK - 1);
            size_t idx = (((size_t)(bb * NHEAD + hh) * DK) + dd) * SEQ + ll;
            dstT[idx] = f2bf(v);
        }
    }
}

// ---------------------------------------------------------------------------
// LSH flash attention, barrier-free main loop.
// Grid (32 q-blocks, 32 b*h), 4 waves; wave w owns q-rows [q0+w*16, +16).
// KV tile = 64 keys. K/V fragments read directly from global (L1/L2-hot);
// only P round-trips through wave-private LDS.
// QK^T: 2-product (q_hi + q_lo) x k_hi.  PV: single product.
// ---------------------------------------------------------------------------
__global__ __launch_bounds__(256) void lsh_attn_kernel(
    const unsigned short* __restrict__ Qhi, const unsigned short* __restrict__ Qlo,
    const unsigned short* __restrict__ Khi, const unsigned short* __restrict__ Vt,
    const int* __restrict__ hash_q, const int* __restrict__ hash_k,
    float* __restrict__ out)
{
    __shared__ unsigned short Pl[4][16][72];   // wave-private P tile [16q][64k]

    const int tid = threadIdx.x;
    const int lane = tid & 63;
    const int wv = tid >> 6;
    const int fr = lane & 15;
    const int fg = lane >> 4;
    const int bh = blockIdx.y;          // b*16 + h
    const int q0 = blockIdx.x * 64;

    const size_t base = (size_t)bh * SEQ * DK;
    const unsigned short* Kb = Khi + base;                  // [key][d]
    const unsigned short* Vb = Vt + (size_t)bh * DK * SEQ;  // [d][k]
    const int* hkp = hash_k + (size_t)bh * SEQ;

    // Q fragments (rows q0 + wv*16 + fr)
    short8_t q_hi[2], q_lo[2];
    {
        const size_t ro = base + (size_t)(q0 + wv * 16 + fr) * DK;
#pragma unroll
        for (int ks = 0; ks < 2; ks++) {
            q_hi[ks] = *(const short8_t*)(Qhi + ro + ks * 32 + fg * 8);
            q_lo[ks] = *(const short8_t*)(Qlo + ro + ks * 32 + fg * 8);
        }
    }
    int hq_r[4];
#pragma unroll
    for (int r = 0; r < 4; r++)
        hq_r[r] = hash_q[(size_t)bh * SEQ + q0 + wv * 16 + fg * 4 + r];

    float m_r[4], l_r[4];
    f32x4 o_acc[4];
    const f32x4 fzero = {0.f, 0.f, 0.f, 0.f};
#pragma unroll
    for (int r = 0; r < 4; r++) { m_r[r] = -INFINITY; l_r[r] = 0.f; }
#pragma unroll
    for (int t = 0; t < 4; t++) o_acc[t] = fzero;

    for (int k0 = 0; k0 < SEQ; k0 += 64) {
        // ---- S = Q K^T : 4 groups of 16 keys ----
        f32x4 s[4];
        int hk[4];
#pragma unroll
        for (int kg = 0; kg < 4; kg++) {
            hk[kg] = hkp[k0 + kg * 16 + fr];
            const unsigned short* kr = Kb + (size_t)(k0 + kg * 16 + fr) * DK + fg * 8;
            short8_t kh0 = *(const short8_t*)(kr);
            short8_t kh1 = *(const short8_t*)(kr + 32);
            f32x4 a = fzero;
            a = MFMA(q_hi[0], kh0, a);
            a = MFMA(q_lo[0], kh0, a);
            a = MFMA(q_hi[1], kh1, a);
            a = MFMA(q_lo[1], kh1, a);
            s[kg] = a;
        }

        // ---- mask + scale + row max (C layout: row=fg*4+r, col=kg*16+fr) ----
        float pmax[4];
#pragma unroll
        for (int r = 0; r < 4; r++) {
            float mx = -INFINITY;
#pragma unroll
            for (int kg = 0; kg < 4; kg++) {
                float v = fmaf(s[kg][r], 0.125f, (hq_r[r] == hk[kg]) ? 0.f : -1e9f);
                s[kg][r] = v;
                mx = fmaxf(mx, v);
            }
            pmax[r] = mx;
        }
#pragma unroll
        for (int d = 1; d < 16; d <<= 1) {
#pragma unroll
            for (int r = 0; r < 4; r++)
                pmax[r] = fmaxf(pmax[r], __shfl_xor(pmax[r], d, 64));
        }

        // ---- online softmax update ----
        float psum[4];
#pragma unroll
        for (int r = 0; r < 4; r++) {
            float mn = fmaxf(m_r[r], pmax[r]);
            float sc = __expf(m_r[r] - mn);   // exp(-inf)=0 on first tile
            m_r[r] = mn;
            l_r[r] *= sc;
#pragma unroll
            for (int t = 0; t < 4; t++) o_acc[t][r] *= sc;
            float ps = 0.f;
#pragma unroll
            for (int kg = 0; kg < 4; kg++) {
                float p = __expf(s[kg][r] - mn);
                Pl[wv][fg * 4 + r][kg * 16 + fr] = f2bf(p);
                ps += p;
            }
            psum[r] = ps;
        }
#pragma unroll
        for (int d = 1; d < 16; d <<= 1) {
#pragma unroll
            for (int r = 0; r < 4; r++)
                psum[r] += __shfl_xor(psum[r], d, 64);
        }
#pragma unroll
        for (int r = 0; r < 4; r++) l_r[r] += psum[r];

        // ---- O += P V  (A = P from wave-private LDS, B = V^T from global) ----
        short8_t pa0 = *(const short8_t*)&Pl[wv][fr][fg * 8];
        short8_t pa1 = *(const short8_t*)&Pl[wv][fr][32 + fg * 8];
#pragma unroll
        for (int dt = 0; dt < 4; dt++) {
            const unsigned short* vr = Vb + (size_t)(dt * 16 + fr) * SEQ + k0 + fg * 8;
            short8_t v0 = *(const short8_t*)(vr);
            short8_t v1 = *(const short8_t*)(vr + 32);
            o_acc[dt] = MFMA(pa0, v0, o_acc[dt]);
            o_acc[dt] = MFMA(pa1, v1, o_acc[dt]);
        }
    }

    // ---- epilogue: out[b, q, h*64 + d] (f32) ----
    const int b = bh >> 4, h = bh & 15;
#pragma unroll
    for (int dt = 0; dt < 4; dt++) {
#pragma unroll
        for (int r = 0; r < 4; r++) {
            int qrow = q0 + wv * 16 + fg * 4 + r;
            int dcol = dt * 16 + fr;
            out[((size_t)(b * SEQ + qrow)) * DMODEL + h * DK + dcol] =
                o_acc[dt][r] / l_r[r];
        }
    }
}

// ---------------------------------------------------------------------------

extern "C" void kernel_launch(void* const* d_in, const int* in_sizes, int n_in,
                              void* d_out, int out_size, void* d_ws, size_t ws_size,
                              hipStream_t stream)
{
    const float* query = (const float*)d_in[0];
    const float* key   = (const float*)d_in[1];
    const float* value = (const float*)d_in[2];
    const int* hash_q  = (const int*)d_in[3];
    const int* hash_k  = (const int*)d_in[4];
    const float* Wq    = (const float*)d_in[5];
    const float* bq    = (const float*)d_in[6];
    const float* Wk    = (const float*)d_in[7];
    const float* bk    = (const float*)d_in[8];
    const float* Wv    = (const float*)d_in[9];
    const float* bv    = (const float*)d_in[10];
    float* out = (float*)d_out;

    const size_t plane = (size_t)BATCH * NHEAD * SEQ * DK;   // 4,194,304 elems
    unsigned short* ws = (unsigned short*)d_ws;               // 4 planes = 32 MB
    unsigned short* pQhi = ws;
    unsigned short* pQlo = ws + plane;
    unsigned short* pKhi = ws + 2 * plane;
    unsigned short* pVt  = ws + 3 * plane;

    dim3 gridN(DMODEL / 64, (BATCH * SEQ) / 64);   // (16, 64)
    proj_nt_kernel<true ><<<gridN, 256, 0, stream>>>(query, Wq, bq, pQhi, pQlo);
    proj_nt_kernel<false><<<gridN, 256, 0, stream>>>(key,   Wk, bk, pKhi, pKhi);

    dim3 gridT((BATCH * SEQ) / 64, DMODEL / 64);   // (64, 16)
    proj_tn_kernel<<<gridT, 256, 0, stream>>>(value, Wv, bv, pVt);

    dim3 agrid(SEQ / 64, BATCH * NHEAD);           // (32, 32)
    lsh_attn_kernel<<<agrid, 256, 0, stream>>>(pQhi, pQlo, pKhi, pVt,
                                               hash_q, hash_k, out);
}

// Round 3
// 351.694 us; speedup vs baseline: 1.3508x; 1.0735x over previous
//
#include <hip/hip_runtime.h>
#include <hip/hip_bf16.h>
#include <stdint.h>
#include <math.h>

#define NHEAD 16
#define DK 64
#define SEQ 2048
#define BATCH 2
#define DMODEL 1024

typedef __attribute__((ext_vector_type(8))) short short8_t;
typedef __attribute__((ext_vector_type(4))) float f32x4;

#define MFMA(a, b, c) __builtin_amdgcn_mfma_f32_16x16x32_bf16(a, b, c, 0, 0, 0)

__device__ __forceinline__ unsigned short f2bf(float f) {
    unsigned int u = __float_as_uint(f);
    u += 0x7fffu + ((u >> 16) & 1u);   // round-to-nearest-even
    return (unsigned short)(u >> 16);
}
__device__ __forceinline__ float bf2f(unsigned short h) {
    return __uint_as_float(((unsigned int)h) << 16);
}

// ---------------------------------------------------------------------------
// proj_nt: dst[b,h,l,d] = (X @ W^T + bias) as bf16 (hi, optionally lo plane).
// Split products kept: ah*bh + ah*bl  (al*bh dropped: ~1.3e-3 rel err).
// ---------------------------------------------------------------------------
template <bool WRITE_LO>
__global__ __launch_bounds__(256) void proj_nt_kernel(
    const float* __restrict__ X, const float* __restrict__ W,
    const float* __restrict__ bias,
    unsigned short* __restrict__ dst_hi, unsigned short* __restrict__ dst_lo)
{
    __shared__ unsigned short Ahi[64][40];
    __shared__ unsigned short Bhi[64][40];
    __shared__ unsigned short Blo[64][40];

    const int tid = threadIdx.x;
    const int lane = tid & 63;
    const int wv = tid >> 6;
    const int fr = lane & 15;
    const int fg = lane >> 4;
    const int m0 = blockIdx.y * 64;
    const int n0 = blockIdx.x * 64;

    const int srow = tid >> 2;          // 0..63
    const int scol = (tid & 3) * 8;     // 0,8,16,24

    f32x4 acc[4];
    const f32x4 fzero = {0.f, 0.f, 0.f, 0.f};
#pragma unroll
    for (int n = 0; n < 4; n++) acc[n] = fzero;

    for (int k0 = 0; k0 < DMODEL; k0 += 32) {
        __syncthreads();
        {
            const float* pa = X + (size_t)(m0 + srow) * DMODEL + k0 + scol;
            const float* pb = W + (size_t)(n0 + srow) * DMODEL + k0 + scol;
            f32x4 a0 = *(const f32x4*)pa;
            f32x4 a1 = *(const f32x4*)(pa + 4);
            f32x4 b0 = *(const f32x4*)pb;
            f32x4 b1 = *(const f32x4*)(pb + 4);
            union { short8_t v; unsigned short u[8]; } ah, bh, bl;
#pragma unroll
            for (int j = 0; j < 4; j++) {
                ah.u[j]     = f2bf(a0[j]);
                ah.u[4 + j] = f2bf(a1[j]);
                float fb = b0[j]; unsigned short h = f2bf(fb);
                bh.u[j] = h; bl.u[j] = f2bf(fb - bf2f(h));
                fb = b1[j]; h = f2bf(fb);
                bh.u[4 + j] = h; bl.u[4 + j] = f2bf(fb - bf2f(h));
            }
            *(short8_t*)&Ahi[srow][scol] = ah.v;
            *(short8_t*)&Bhi[srow][scol] = bh.v;
            *(short8_t*)&Blo[srow][scol] = bl.v;
        }
        __syncthreads();

        short8_t a_hi = *(const short8_t*)&Ahi[wv * 16 + fr][fg * 8];
#pragma unroll
        for (int n = 0; n < 4; n++) {
            short8_t b_hi = *(const short8_t*)&Bhi[n * 16 + fr][fg * 8];
            short8_t b_lo = *(const short8_t*)&Blo[n * 16 + fr][fg * 8];
            acc[n] = MFMA(a_hi, b_hi, acc[n]);
            acc[n] = MFMA(a_hi, b_lo, acc[n]);
        }
    }

    // C row = m0 + wv*16 + fg*4 + r ; col = n0 + n*16 + fr
#pragma unroll
    for (int n = 0; n < 4; n++) {
#pragma unroll
        for (int r = 0; r < 4; r++) {
            int gm = m0 + wv * 16 + fg * 4 + r;     // b*2048 + l
            int go = n0 + n * 16 + fr;              // h*64 + d
            float v = acc[n][r] + bias[go];
            int bb = gm >> 11;
            int ll = gm & (SEQ - 1);
            int hh = go >> 6;
            int dd = go & (DK - 1);
            size_t idx = (((size_t)(bb * NHEAD + hh) * SEQ) + ll) * DK + dd;
            unsigned short h = f2bf(v);
            dst_hi[idx] = h;
            if constexpr (WRITE_LO) dst_lo[idx] = f2bf(v - bf2f(h));
        }
    }
}

// ---------------------------------------------------------------------------
// proj_tn: dstT[b,h,d,l] = (X @ W^T + bias)^T as bf16 hi.
// A = W rows, B = X rows -> C transposed. Products: Wh*Xh + Wh*Xl.
// ---------------------------------------------------------------------------
__global__ __launch_bounds__(256) void proj_tn_kernel(
    const float* __restrict__ X, const float* __restrict__ W,
    const float* __restrict__ bias, unsigned short* __restrict__ dstT)
{
    __shared__ unsigned short Ahi[64][40];
    __shared__ unsigned short Bhi[64][40];
    __shared__ unsigned short Blo[64][40];

    const int tid = threadIdx.x;
    const int lane = tid & 63;
    const int wv = tid >> 6;
    const int fr = lane & 15;
    const int fg = lane >> 4;
    const int m0 = blockIdx.x * 64;     // rows of X (b*l)
    const int n0 = blockIdx.y * 64;     // out-dims

    const int srow = tid >> 2;
    const int scol = (tid & 3) * 8;

    f32x4 acc[4];
    const f32x4 fzero = {0.f, 0.f, 0.f, 0.f};
#pragma unroll
    for (int j = 0; j < 4; j++) acc[j] = fzero;

    for (int k0 = 0; k0 < DMODEL; k0 += 32) {
        __syncthreads();
        {
            const float* pa = W + (size_t)(n0 + srow) * DMODEL + k0 + scol;  // A = W
            const float* pb = X + (size_t)(m0 + srow) * DMODEL + k0 + scol;  // B = X
            f32x4 a0 = *(const f32x4*)pa;
            f32x4 a1 = *(const f32x4*)(pa + 4);
            f32x4 b0 = *(const f32x4*)pb;
            f32x4 b1 = *(const f32x4*)(pb + 4);
            union { short8_t v; unsigned short u[8]; } ah, bh, bl;
#pragma unroll
            for (int j = 0; j < 4; j++) {
                ah.u[j]     = f2bf(a0[j]);
                ah.u[4 + j] = f2bf(a1[j]);
                float fb = b0[j]; unsigned short h = f2bf(fb);
                bh.u[j] = h; bl.u[j] = f2bf(fb - bf2f(h));
                fb = b1[j]; h = f2bf(fb);
                bh.u[4 + j] = h; bl.u[4 + j] = f2bf(fb - bf2f(h));
            }
            *(short8_t*)&Ahi[srow][scol] = ah.v;
            *(short8_t*)&Bhi[srow][scol] = bh.v;
            *(short8_t*)&Blo[srow][scol] = bl.v;
        }
        __syncthreads();

        short8_t a_hi = *(const short8_t*)&Ahi[wv * 16 + fr][fg * 8];
#pragma unroll
        for (int j = 0; j < 4; j++) {
            short8_t b_hi = *(const short8_t*)&Bhi[j * 16 + fr][fg * 8];
            short8_t b_lo = *(const short8_t*)&Blo[j * 16 + fr][fg * 8];
            acc[j] = MFMA(a_hi, b_hi, acc[j]);
            acc[j] = MFMA(a_hi, b_lo, acc[j]);
        }
    }

    // C row = out-dim = n0 + wv*16 + fg*4 + r ; col = m = m0 + j*16 + fr
#pragma unroll
    for (int j = 0; j < 4; j++) {
#pragma unroll
        for (int r = 0; r < 4; r++) {
            int od = n0 + wv * 16 + fg * 4 + r;     // h*64 + d
            int gm = m0 + j * 16 + fr;              // b*2048 + l
            float v = acc[j][r] + bias[od];
            int bb = gm >> 11;
            int ll = gm & (SEQ - 1);
            int hh = od >> 6;
            int dd = od & (DK - 1);
            size_t idx = (((size_t)(bb * NHEAD + hh) * DK) + dd) * SEQ + ll;
            dstT[idx] = f2bf(v);
        }
    }
}

// ---------------------------------------------------------------------------
// LSH flash attention, barrier-free, static-max softmax, K-prefetch,
// XCD-grouped heads (each XCD owns 4 heads -> 2MB KV set fits its L2).
// Grid flat = 1024 blocks; 4 waves; wave w owns q-rows [q0+w*16, +16).
// ---------------------------------------------------------------------------
__global__ __launch_bounds__(256) void lsh_attn_kernel(
    const unsigned short* __restrict__ Qhi, const unsigned short* __restrict__ Qlo,
    const unsigned short* __restrict__ Khi, const unsigned short* __restrict__ Vt,
    const int* __restrict__ hash_q, const int* __restrict__ hash_k,
    float* __restrict__ out)
{
    __shared__ unsigned short Pl[4][16][72];   // wave-private P tile [16q][64k]

    const int tid = threadIdx.x;
    const int lane = tid & 63;
    const int wv = tid >> 6;
    const int fr = lane & 15;
    const int fg = lane >> 4;

    // XCD-aware remap: block n -> XCD n%8; give XCD x heads [4x, 4x+4).
    const int flat = blockIdx.y * gridDim.x + blockIdx.x;   // 0..1023
    const int xcd = flat & 7;
    const int slot = flat >> 3;                              // 0..127
    const int bh = (xcd << 2) + (slot >> 5);                 // b*16 + h
    const int q0 = (slot & 31) << 6;

    const size_t base = (size_t)bh * SEQ * DK;
    const unsigned short* Kb = Khi + base;                  // [key][d]
    const unsigned short* Vb = Vt + (size_t)bh * DK * SEQ;  // [d][k]
    const int* hkp = hash_k + (size_t)bh * SEQ;

    // Q fragments (rows q0 + wv*16 + fr)
    short8_t q_hi[2], q_lo[2];
    {
        const size_t ro = base + (size_t)(q0 + wv * 16 + fr) * DK;
#pragma unroll
        for (int ks = 0; ks < 2; ks++) {
            q_hi[ks] = *(const short8_t*)(Qhi + ro + ks * 32 + fg * 8);
            q_lo[ks] = *(const short8_t*)(Qlo + ro + ks * 32 + fg * 8);
        }
    }
    int hq_r[4];
#pragma unroll
    for (int r = 0; r < 4; r++)
        hq_r[r] = hash_q[(size_t)bh * SEQ + q0 + wv * 16 + fg * 4 + r];

    float psum[4] = {0.f, 0.f, 0.f, 0.f};
    f32x4 o_acc[4];
    const f32x4 fzero = {0.f, 0.f, 0.f, 0.f};
#pragma unroll
    for (int t = 0; t < 4; t++) o_acc[t] = fzero;

    // preload K tile 0 fragments + hashes
    short8_t kc0[4], kc1[4];
    int hkc[4];
#pragma unroll
    for (int kg = 0; kg < 4; kg++) {
        const unsigned short* kr = Kb + (size_t)(kg * 16 + fr) * DK + fg * 8;
        kc0[kg] = *(const short8_t*)kr;
        kc1[kg] = *(const short8_t*)(kr + 32);
        hkc[kg] = hkp[kg * 16 + fr];
    }

    for (int k0 = 0; k0 < SEQ; k0 += 64) {
        // ---- S = Q K^T (16 MFMA, split q) ----
        f32x4 s[4];
#pragma unroll
        for (int kg = 0; kg < 4; kg++) {
            f32x4 a = fzero;
            a = MFMA(q_hi[0], kc0[kg], a);
            a = MFMA(q_lo[0], kc0[kg], a);
            a = MFMA(q_hi[1], kc1[kg], a);
            a = MFMA(q_lo[1], kc1[kg], a);
            s[kg] = a;
        }
        int hk[4];
#pragma unroll
        for (int kg = 0; kg < 4; kg++) hk[kg] = hkc[kg];

        // ---- prefetch next K tile into same regs (after MFMA consumed) ----
        if (k0 + 64 < SEQ) {
#pragma unroll
            for (int kg = 0; kg < 4; kg++) {
                const unsigned short* kr =
                    Kb + (size_t)(k0 + 64 + kg * 16 + fr) * DK + fg * 8;
                kc0[kg] = *(const short8_t*)kr;
                kc1[kg] = *(const short8_t*)(kr + 32);
                hkc[kg] = hkp[k0 + 64 + kg * 16 + fr];
            }
        }

        // ---- issue V loads early (consumed after softmax) ----
        short8_t v0[4], v1[4];
#pragma unroll
        for (int dt = 0; dt < 4; dt++) {
            const unsigned short* vr = Vb + (size_t)(dt * 16 + fr) * SEQ + k0 + fg * 8;
            v0[dt] = *(const short8_t*)(vr);
            v1[dt] = *(const short8_t*)(vr + 32);
        }

        // ---- static-max softmax: p = exp(s/8 - 10); masked -> exp(-1e9)=0 ----
#pragma unroll
        for (int r = 0; r < 4; r++) {
#pragma unroll
            for (int kg = 0; kg < 4; kg++) {
                float basev = (hq_r[r] == hk[kg]) ? -10.0f : -1e9f;
                float p = __expf(fmaf(s[kg][r], 0.125f, basev));
                psum[r] += p;
                Pl[wv][fg * 4 + r][kg * 16 + fr] = f2bf(p);
            }
        }

        // ---- O += P V ----
        short8_t pa0 = *(const short8_t*)&Pl[wv][fr][fg * 8];
        short8_t pa1 = *(const short8_t*)&Pl[wv][fr][32 + fg * 8];
#pragma unroll
        for (int dt = 0; dt < 4; dt++) {
            o_acc[dt] = MFMA(pa0, v0[dt], o_acc[dt]);
            o_acc[dt] = MFMA(pa1, v1[dt], o_acc[dt]);
        }
    }

    // ---- one final l-reduction over the 16 fr lanes ----
#pragma unroll
    for (int d = 1; d < 16; d <<= 1) {
#pragma unroll
        for (int r = 0; r < 4; r++) psum[r] += __shfl_xor(psum[r], d, 64);
    }

    // ---- epilogue: out[b, q, h*64 + d] (f32) ----
    const int b = bh >> 4, h = bh & 15;
#pragma unroll
    for (int dt = 0; dt < 4; dt++) {
#pragma unroll
        for (int r = 0; r < 4; r++) {
            int qrow = q0 + wv * 16 + fg * 4 + r;
            int dcol = dt * 16 + fr;
            out[((size_t)(b * SEQ + qrow)) * DMODEL + h * DK + dcol] =
                o_acc[dt][r] / psum[r];
        }
    }
}

// ---------------------------------------------------------------------------

extern "C" void kernel_launch(void* const* d_in, const int* in_sizes, int n_in,
                              void* d_out, int out_size, void* d_ws, size_t ws_size,
                              hipStream_t stream)
{
    const float* query = (const float*)d_in[0];
    const float* key   = (const float*)d_in[1];
    const float* value = (const float*)d_in[2];
    const int* hash_q  = (const int*)d_in[3];
    const int* hash_k  = (const int*)d_in[4];
    const float* Wq    = (const float*)d_in[5];
    const float* bq    = (const float*)d_in[6];
    const float* Wk    = (const float*)d_in[7];
    const float* bk    = (const float*)d_in[8];
    const float* Wv    = (const float*)d_in[9];
    const float* bv    = (const float*)d_in[10];
    float* out = (float*)d_out;

    const size_t plane = (size_t)BATCH * NHEAD * SEQ * DK;   // 4,194,304 elems
    unsigned short* ws = (unsigned short*)d_ws;               // 4 planes = 32 MB
    unsigned short* pQhi = ws;
    unsigned short* pQlo = ws + plane;
    unsigned short* pKhi = ws + 2 * plane;
    unsigned short* pVt  = ws + 3 * plane;

    dim3 gridN(DMODEL / 64, (BATCH * SEQ) / 64);   // (16, 64)
    proj_nt_kernel<true ><<<gridN, 256, 0, stream>>>(query, Wq, bq, pQhi, pQlo);
    proj_nt_kernel<false><<<gridN, 256, 0, stream>>>(key,   Wk, bk, pKhi, pKhi);

    dim3 gridT((BATCH * SEQ) / 64, DMODEL / 64);   // (64, 16)
    proj_tn_kernel<<<gridT, 256, 0, stream>>>(value, Wv, bv, pVt);

    dim3 agrid(SEQ / 64, BATCH * NHEAD);           // (32, 32)
    lsh_attn_kernel<<<agrid, 256, 0, stream>>>(pQhi, pQlo, pKhi, pVt,
                                               hash_q, hash_k, out);
}

// Round 4
// 193.514 us; speedup vs baseline: 2.4550x; 1.8174x over previous
//
#include <hip/hip_runtime.h>
#include <hip/hip_bf16.h>
#include <stdint.h>
#include <math.h>

#define NHEAD 16
#define DK 64
#define SEQ 2048
#define BATCH 2
#define DMODEL 1024

typedef __attribute__((ext_vector_type(8))) short short8_t;
typedef __attribute__((ext_vector_type(4))) float f32x4;

#define MFMA(a, b, c) __builtin_amdgcn_mfma_f32_16x16x32_bf16(a, b, c, 0, 0, 0)

__device__ __forceinline__ unsigned short f2bf(float f) {
    unsigned int u = __float_as_uint(f);
    u += 0x7fffu + ((u >> 16) & 1u);   // round-to-nearest-even
    return (unsigned short)(u >> 16);
}
__device__ __forceinline__ float bf2f(unsigned short h) {
    return __uint_as_float(((unsigned int)h) << 16);
}

// ---------------------------------------------------------------------------
// proj_nt: dst[b,h,l,d] = (X @ W^T + bias) as bf16.
// Split products kept: ah*bh + ah*bl.
// ---------------------------------------------------------------------------
__global__ __launch_bounds__(256) void proj_nt_kernel(
    const float* __restrict__ X, const float* __restrict__ W,
    const float* __restrict__ bias, unsigned short* __restrict__ dst_hi)
{
    __shared__ unsigned short Ahi[64][40];
    __shared__ unsigned short Bhi[64][40];
    __shared__ unsigned short Blo[64][40];

    const int tid = threadIdx.x;
    const int lane = tid & 63;
    const int wv = tid >> 6;
    const int fr = lane & 15;
    const int fg = lane >> 4;
    const int m0 = blockIdx.y * 64;
    const int n0 = blockIdx.x * 64;

    const int srow = tid >> 2;          // 0..63
    const int scol = (tid & 3) * 8;     // 0,8,16,24

    f32x4 acc[4];
    const f32x4 fzero = {0.f, 0.f, 0.f, 0.f};
#pragma unroll
    for (int n = 0; n < 4; n++) acc[n] = fzero;

    for (int k0 = 0; k0 < DMODEL; k0 += 32) {
        __syncthreads();
        {
            const float* pa = X + (size_t)(m0 + srow) * DMODEL + k0 + scol;
            const float* pb = W + (size_t)(n0 + srow) * DMODEL + k0 + scol;
            f32x4 a0 = *(const f32x4*)pa;
            f32x4 a1 = *(const f32x4*)(pa + 4);
            f32x4 b0 = *(const f32x4*)pb;
            f32x4 b1 = *(const f32x4*)(pb + 4);
            union { short8_t v; unsigned short u[8]; } ah, bh, bl;
#pragma unroll
            for (int j = 0; j < 4; j++) {
                ah.u[j]     = f2bf(a0[j]);
                ah.u[4 + j] = f2bf(a1[j]);
                float fb = b0[j]; unsigned short h = f2bf(fb);
                bh.u[j] = h; bl.u[j] = f2bf(fb - bf2f(h));
                fb = b1[j]; h = f2bf(fb);
                bh.u[4 + j] = h; bl.u[4 + j] = f2bf(fb - bf2f(h));
            }
            *(short8_t*)&Ahi[srow][scol] = ah.v;
            *(short8_t*)&Bhi[srow][scol] = bh.v;
            *(short8_t*)&Blo[srow][scol] = bl.v;
        }
        __syncthreads();

        short8_t a_hi = *(const short8_t*)&Ahi[wv * 16 + fr][fg * 8];
#pragma unroll
        for (int n = 0; n < 4; n++) {
            short8_t b_hi = *(const short8_t*)&Bhi[n * 16 + fr][fg * 8];
            short8_t b_lo = *(const short8_t*)&Blo[n * 16 + fr][fg * 8];
            acc[n] = MFMA(a_hi, b_hi, acc[n]);
            acc[n] = MFMA(a_hi, b_lo, acc[n]);
        }
    }

    // C row = m0 + wv*16 + fg*4 + r ; col = n0 + n*16 + fr
#pragma unroll
    for (int n = 0; n < 4; n++) {
#pragma unroll
        for (int r = 0; r < 4; r++) {
            int gm = m0 + wv * 16 + fg * 4 + r;     // b*2048 + l
            int go = n0 + n * 16 + fr;              // h*64 + d
            float v = acc[n][r] + bias[go];
            int bb = gm >> 11;
            int ll = gm & (SEQ - 1);
            int hh = go >> 6;
            int dd = go & (DK - 1);
            size_t idx = (((size_t)(bb * NHEAD + hh) * SEQ) + ll) * DK + dd;
            dst_hi[idx] = f2bf(v);
        }
    }
}

// ---------------------------------------------------------------------------
// proj_tn: dstT[b,h,d,l] = (X @ W^T + bias)^T as bf16.
// ---------------------------------------------------------------------------
__global__ __launch_bounds__(256) void proj_tn_kernel(
    const float* __restrict__ X, const float* __restrict__ W,
    const float* __restrict__ bias, unsigned short* __restrict__ dstT)
{
    __shared__ unsigned short Ahi[64][40];
    __shared__ unsigned short Bhi[64][40];
    __shared__ unsigned short Blo[64][40];

    const int tid = threadIdx.x;
    const int lane = tid & 63;
    const int wv = tid >> 6;
    const int fr = lane & 15;
    const int fg = lane >> 4;
    const int m0 = blockIdx.x * 64;     // rows of X (b*l)
    const int n0 = blockIdx.y * 64;     // out-dims

    const int srow = tid >> 2;
    const int scol = (tid & 3) * 8;

    f32x4 acc[4];
    const f32x4 fzero = {0.f, 0.f, 0.f, 0.f};
#pragma unroll
    for (int j = 0; j < 4; j++) acc[j] = fzero;

    for (int k0 = 0; k0 < DMODEL; k0 += 32) {
        __syncthreads();
        {
            const float* pa = W + (size_t)(n0 + srow) * DMODEL + k0 + scol;  // A = W
            const float* pb = X + (size_t)(m0 + srow) * DMODEL + k0 + scol;  // B = X
            f32x4 a0 = *(const f32x4*)pa;
            f32x4 a1 = *(const f32x4*)(pa + 4);
            f32x4 b0 = *(const f32x4*)pb;
            f32x4 b1 = *(const f32x4*)(pb + 4);
            union { short8_t v; unsigned short u[8]; } ah, bh, bl;
#pragma unroll
            for (int j = 0; j < 4; j++) {
                ah.u[j]     = f2bf(a0[j]);
                ah.u[4 + j] = f2bf(a1[j]);
                float fb = b0[j]; unsigned short h = f2bf(fb);
                bh.u[j] = h; bl.u[j] = f2bf(fb - bf2f(h));
                fb = b1[j]; h = f2bf(fb);
                bh.u[4 + j] = h; bl.u[4 + j] = f2bf(fb - bf2f(h));
            }
            *(short8_t*)&Ahi[srow][scol] = ah.v;
            *(short8_t*)&Bhi[srow][scol] = bh.v;
            *(short8_t*)&Blo[srow][scol] = bl.v;
        }
        __syncthreads();

        short8_t a_hi = *(const short8_t*)&Ahi[wv * 16 + fr][fg * 8];
#pragma unroll
        for (int j = 0; j < 4; j++) {
            short8_t b_hi = *(const short8_t*)&Bhi[j * 16 + fr][fg * 8];
            short8_t b_lo = *(const short8_t*)&Blo[j * 16 + fr][fg * 8];
            acc[j] = MFMA(a_hi, b_hi, acc[j]);
            acc[j] = MFMA(a_hi, b_lo, acc[j]);
        }
    }

    // C row = out-dim = n0 + wv*16 + fg*4 + r ; col = m = m0 + j*16 + fr
#pragma unroll
    for (int j = 0; j < 4; j++) {
#pragma unroll
        for (int r = 0; r < 4; r++) {
            int od = n0 + wv * 16 + fg * 4 + r;     // h*64 + d
            int gm = m0 + j * 16 + fr;              // b*2048 + l
            float v = acc[j][r] + bias[od];
            int bb = gm >> 11;
            int ll = gm & (SEQ - 1);
            int hh = od >> 6;
            int dd = od & (DK - 1);
            size_t idx = (((size_t)(bb * NHEAD + hh) * DK) + dd) * SEQ + ll;
            dstT[idx] = f2bf(v);
        }
    }
}

// ---------------------------------------------------------------------------
// LSH flash attention with cooperative LDS staging.
// ---------------------------------------------------------------------------
__global__ __launch_bounds__(256) void lsh_attn_kernel(
    const unsigned short* __restrict__ Qhi,
    const unsigned short* __restrict__ Khi, const unsigned short* __restrict__ Vt,
    const int* __restrict__ hash_q, const int* __restrict__ hash_k,
    float* __restrict__ out)
{
    __shared__ unsigned short KtL[64 * 64];   // [key][d], 16B-units XOR-swizzled
    __shared__ unsigned short VtL[64 * 64];   // [d][k],   16B-units XOR-swizzled
    __shared__ unsigned short Pl[4][16][72];  // wave-private P tile

    const int tid = threadIdx.x;
    const int lane = tid & 63;
    const int wv = tid >> 6;
    const int fr = lane & 15;
    const int fg = lane >> 4;

    // XCD-aware remap: XCD x owns heads [4x, 4x+4).
    const int flat = blockIdx.x;                 // 0..1023
    const int xcd = flat & 7;
    const int slot = flat >> 3;                  // 0..127
    const int bh = (xcd << 2) + (slot >> 5);     // b*16 + h
    const int q0 = (slot & 31) << 6;

    const size_t base = (size_t)bh * SEQ * DK;
    const unsigned short* Kb = Khi + base;                  // [key][d]
    const unsigned short* Vb = Vt + (size_t)bh * DK * SEQ;  // [d][k]
    const int* hkp = hash_k + (size_t)bh * SEQ;

    // staging lane constants: within an inst, lane -> row (lane>>3), unit (lane&7)
    const int srw = lane >> 3;    // 0..7
    const int su = lane & 7;      // 16B unit within a 128B row

    // Q fragments (rows q0 + wv*16 + fr), hi plane only
    short8_t q_hi[2];
    {
        const size_t ro = base + (size_t)(q0 + wv * 16 + fr) * DK;
        q_hi[0] = *(const short8_t*)(Qhi + ro + fg * 8);
        q_hi[1] = *(const short8_t*)(Qhi + ro + 32 + fg * 8);
    }
    int hq_r[4];
#pragma unroll
    for (int r = 0; r < 4; r++)
        hq_r[r] = hash_q[(size_t)bh * SEQ + q0 + wv * 16 + fg * 4 + r];

    const int swz = fr & 7;                  // read-side XOR (row & 7 == fr & 7)
    const int u0 = ((fg ^ swz) << 3);        // element offset, units 0..3
    const int u1 = (((4 + fg) ^ swz) << 3);  // element offset, units 4..7

    float psum[4] = {0.f, 0.f, 0.f, 0.f};
    f32x4 o_acc[4];
    const f32x4 fzero = {0.f, 0.f, 0.f, 0.f};
#pragma unroll
    for (int t = 0; t < 4; t++) o_acc[t] = fzero;

    for (int k0 = 0; k0 < SEQ; k0 += 64) {
        // ---- cooperative stage: wave wv stages tile rows [wv*16, wv*16+16) ----
#pragma unroll
        for (int i = 0; i < 2; i++) {
            const int r = wv * 16 + i * 8 + srw;          // tile row 0..63
            const int uo = ((su ^ (r & 7)) << 3);         // swizzled source unit
            const unsigned short* gk = Kb + (size_t)(k0 + r) * DK + uo;
            const unsigned short* gv = Vb + (size_t)r * SEQ + k0 + uo;
            __builtin_amdgcn_global_load_lds(
                (const void*)gk, (void*)&KtL[(wv * 16 + i * 8) * 64], 16, 0, 0);
            __builtin_amdgcn_global_load_lds(
                (const void*)gv, (void*)&VtL[(wv * 16 + i * 8) * 64], 16, 0, 0);
        }

        // hashes for this tile (per-lane, cache-hot)
        int hk[4];
#pragma unroll
        for (int kg = 0; kg < 4; kg++) hk[kg] = hkp[k0 + kg * 16 + fr];

        __syncthreads();   // drains vmcnt/lgkmcnt: staged tile visible

        // ---- S = Q K^T (8 MFMA) ----
        f32x4 s[4];
#pragma unroll
        for (int kg = 0; kg < 4; kg++) {
            const int rr = (kg * 16 + fr) * 64;
            short8_t kc0 = *(const short8_t*)&KtL[rr + u0];
            short8_t kc1 = *(const short8_t*)&KtL[rr + u1];
            f32x4 a = fzero;
            a = MFMA(q_hi[0], kc0, a);
            a = MFMA(q_hi[1], kc1, a);
            s[kg] = a;
        }

        // ---- static-max softmax: p = exp(s/8 - 10); masked -> 0 ----
#pragma unroll
        for (int r = 0; r < 4; r++) {
#pragma unroll
            for (int kg = 0; kg < 4; kg++) {
                float basev = (hq_r[r] == hk[kg]) ? -10.0f : -1e9f;
                float p = __expf(fmaf(s[kg][r], 0.125f, basev));
                psum[r] += p;
                Pl[wv][fg * 4 + r][kg * 16 + fr] = f2bf(p);
            }
        }

        // ---- O += P V ----
        short8_t pa0 = *(const short8_t*)&Pl[wv][fr][fg * 8];
        short8_t pa1 = *(const short8_t*)&Pl[wv][fr][32 + fg * 8];
#pragma unroll
        for (int dt = 0; dt < 4; dt++) {
            const int rr = (dt * 16 + fr) * 64;
            short8_t v0 = *(const short8_t*)&VtL[rr + u0];
            short8_t v1 = *(const short8_t*)&VtL[rr + u1];
            o_acc[dt] = MFMA(pa0, v0, o_acc[dt]);
            o_acc[dt] = MFMA(pa1, v1, o_acc[dt]);
        }

        __syncthreads();   // tile fully consumed before restage
    }

    // ---- final l-reduction over the 16 fr lanes ----
#pragma unroll
    for (int d = 1; d < 16; d <<= 1) {
#pragma unroll
        for (int r = 0; r < 4; r++) psum[r] += __shfl_xor(psum[r], d, 64);
    }

    // ---- epilogue: out[b, q, h*64 + d] (f32) ----
    const int b = bh >> 4, h = bh & 15;
#pragma unroll
    for (int dt = 0; dt < 4; dt++) {
#pragma unroll
        for (int r = 0; r < 4; r++) {
            int qrow = q0 + wv * 16 + fg * 4 + r;
            int dcol = dt * 16 + fr;
            out[((size_t)(b * SEQ + qrow)) * DMODEL + h * DK + dcol] =
                o_acc[dt][r] / psum[r];
        }
    }
}

// ---------------------------------------------------------------------------

extern "C" void kernel_launch(void* const* d_in, const int* in_sizes, int n_in,
                              void* d_out, int out_size, void* d_ws, size_t ws_size,
                              hipStream_t stream)
{
    const float* query = (const float*)d_in[0];
    const float* key   = (const float*)d_in[1];
    const float* value = (const float*)d_in[2];
    const int* hash_q  = (const int*)d_in[3];
    const int* hash_k  = (const int*)d_in[4];
    const float* Wq    = (const float*)d_in[5];
    const float* bq    = (const float*)d_in[6];
    const float* Wk    = (const float*)d_in[7];
    const float* bk    = (const float*)d_in[8];
    const float* Wv    = (const float*)d_in[9];
    const float* bv    = (const float*)d_in[10];
    float* out = (float*)d_out;

    const size_t plane = (size_t)BATCH * NHEAD * SEQ * DK;   // 4,194,304 elems
    unsigned short* ws = (unsigned short*)d_ws;               // 3 planes = 24 MB
    unsigned short* pQhi = ws;
    unsigned short* pKhi = ws + plane;
    unsigned short* pVt  = ws + 2 * plane;

    dim3 gridN(DMODEL / 64, (BATCH * SEQ) / 64);   // (16, 64)
    proj_nt_kernel<<<gridN, 256, 0, stream>>>(query, Wq, bq, pQhi);
    proj_nt_kernel<<<gridN, 256, 0, stream>>>(key,   Wk, bk, pKhi);

    dim3 gridT((BATCH * SEQ) / 64, DMODEL / 64);   // (64, 16)
    proj_tn_kernel<<<gridT, 256, 0, stream>>>(value, Wv, bv, pVt);

    lsh_attn_kernel<<<dim3(1024), 256, 0, stream>>>(pQhi, pKhi, pVt,
                                                    hash_q, hash_k, out);
}

// Round 5
// 141.233 us; speedup vs baseline: 3.3637x; 1.3702x over previous
//
#include <hip/hip_runtime.h>
#include <hip/hip_bf16.h>
#include <stdint.h>
#include <math.h>

#define NHEAD 16
#define DK 64
#define SEQ 2048
#define BATCH 2
#define DMODEL 1024

typedef __attribute__((ext_vector_type(8))) short short8_t;
typedef __attribute__((ext_vector_type(4))) float f32x4;

#define MFMA(a, b, c) __builtin_amdgcn_mfma_f32_16x16x32_bf16(a, b, c, 0, 0, 0)

__device__ __forceinline__ unsigned short f2bf(float f) {
    union { __hip_bfloat16 b; unsigned short u; } c;
    c.b = __float2bfloat16(f);   // RNE; compiler emits v_cvt_pk_bf16_f32
    return c.u;
}

// ---------------------------------------------------------------------------
// cvt_xw: X (4M f32) -> bf16, W (1M f32) -> bf16. 8 els/thread, vectorized.
// ---------------------------------------------------------------------------
__global__ __launch_bounds__(256) void cvt_xw_kernel(
    const float* __restrict__ X, const float* __restrict__ W,
    unsigned short* __restrict__ Xb, unsigned short* __restrict__ Wb)
{
    const size_t t = (size_t)blockIdx.x * 256 + threadIdx.x;  // 0..655359
    const float* src;
    unsigned short* dst;
    size_t i8;
    if (t < 524288) { src = X; dst = Xb; i8 = t * 8; }
    else            { src = W; dst = Wb; i8 = (t - 524288) * 8; }
    f32x4 v0 = *(const f32x4*)(src + i8);
    f32x4 v1 = *(const f32x4*)(src + i8 + 4);
    union { short8_t v; unsigned short u[8]; } o;
#pragma unroll
    for (int j = 0; j < 4; j++) {
        o.u[j]     = f2bf(v0[j]);
        o.u[4 + j] = f2bf(v1[j]);
    }
    *(short8_t*)(dst + i8) = o.v;
}

// ---------------------------------------------------------------------------
// proj_nt_bf16: dst[b,h,l,d] = Xb @ Wb^T + bias (pure bf16 MFMA).
// Tile 128(M) x 64(N), BK=64, 4 waves; wave owns 32m x 64n (2x4 frags).
// global_load_lds staging, XOR-unit swizzle (linear dest + swizzled src).
// ---------------------------------------------------------------------------
__global__ __launch_bounds__(256) void proj_nt_bf16(
    const unsigned short* __restrict__ Xb,   // [4096][1024]
    const unsigned short* __restrict__ Wb,   // [1024][1024]
    const float* __restrict__ bias,
    unsigned short* __restrict__ dst)        // [b,h,l,d] bf16
{
    __shared__ unsigned short At[128 * 64];
    __shared__ unsigned short Bt[64 * 64];

    const int tid = threadIdx.x;
    const int lane = tid & 63;
    const int wv = tid >> 6;
    const int fr = lane & 15;
    const int fg = lane >> 4;
    const int m0 = blockIdx.y * 128;
    const int n0 = blockIdx.x * 64;
    const int srw = lane >> 3;   // 0..7
    const int su = lane & 7;     // 16B unit

    f32x4 acc[2][4];
    const f32x4 fzero = {0.f, 0.f, 0.f, 0.f};
#pragma unroll
    for (int mf = 0; mf < 2; mf++)
#pragma unroll
        for (int nf = 0; nf < 4; nf++) acc[mf][nf] = fzero;

    for (int k0 = 0; k0 < DMODEL; k0 += 64) {
        // ---- stage A (wave: rows wv*32..+32) and B (rows wv*16..+16) ----
#pragma unroll
        for (int i = 0; i < 4; i++) {
            int r = wv * 32 + i * 8 + srw;
            const unsigned short* g =
                Xb + (size_t)(m0 + r) * DMODEL + k0 + ((su ^ (r & 7)) << 3);
            __builtin_amdgcn_global_load_lds(
                (const void*)g, (void*)&At[(wv * 32 + i * 8) * 64], 16, 0, 0);
        }
#pragma unroll
        for (int i = 0; i < 2; i++) {
            int r = wv * 16 + i * 8 + srw;
            const unsigned short* g =
                Wb + (size_t)(n0 + r) * DMODEL + k0 + ((su ^ (r & 7)) << 3);
            __builtin_amdgcn_global_load_lds(
                (const void*)g, (void*)&Bt[(wv * 16 + i * 8) * 64], 16, 0, 0);
        }
        __syncthreads();

        short8_t a[2][2], b[4][2];
#pragma unroll
        for (int mf = 0; mf < 2; mf++)
#pragma unroll
            for (int ks = 0; ks < 2; ks++) {
                int r = wv * 32 + mf * 16 + fr;
                int u = (ks * 4 + fg) ^ (fr & 7);
                a[mf][ks] = *(const short8_t*)&At[r * 64 + u * 8];
            }
#pragma unroll
        for (int nf = 0; nf < 4; nf++)
#pragma unroll
            for (int ks = 0; ks < 2; ks++) {
                int r = nf * 16 + fr;
                int u = (ks * 4 + fg) ^ (fr & 7);
                b[nf][ks] = *(const short8_t*)&Bt[r * 64 + u * 8];
            }
#pragma unroll
        for (int ks = 0; ks < 2; ks++)
#pragma unroll
            for (int mf = 0; mf < 2; mf++)
#pragma unroll
                for (int nf = 0; nf < 4; nf++)
                    acc[mf][nf] = MFMA(a[mf][ks], b[nf][ks], acc[mf][nf]);
        __syncthreads();
    }

    // epilogue: row = m0 + wv*32 + mf*16 + fg*4 + r ; col = n0 + nf*16 + fr
#pragma unroll
    for (int mf = 0; mf < 2; mf++)
#pragma unroll
        for (int nf = 0; nf < 4; nf++)
#pragma unroll
            for (int r = 0; r < 4; r++) {
                int gm = m0 + wv * 32 + mf * 16 + fg * 4 + r;  // b*2048 + l
                int go = n0 + nf * 16 + fr;                    // h*64 + d
                float v = acc[mf][nf][r] + bias[go];
                int bb = gm >> 11, ll = gm & (SEQ - 1);
                int hh = go >> 6, dd = go & (DK - 1);
                dst[(((size_t)(bb * NHEAD + hh) * SEQ) + ll) * DK + dd] = f2bf(v);
            }
}

// ---------------------------------------------------------------------------
// proj_tn_bf16: dstT[b,h,d,l] = (Xb @ Wb^T + bias)^T  (A = W rows, B = X rows).
// Tile 128(O) x 64(M), BK=64.
// ---------------------------------------------------------------------------
__global__ __launch_bounds__(256) void proj_tn_bf16(
    const unsigned short* __restrict__ Xb,   // [4096][1024]
    const unsigned short* __restrict__ Wb,   // [1024][1024]
    const float* __restrict__ bias,
    unsigned short* __restrict__ dstT)       // [b,h,d,l] bf16
{
    __shared__ unsigned short At[128 * 64];
    __shared__ unsigned short Bt[64 * 64];

    const int tid = threadIdx.x;
    const int lane = tid & 63;
    const int wv = tid >> 6;
    const int fr = lane & 15;
    const int fg = lane >> 4;
    const int o0 = blockIdx.y * 128;    // out-dims
    const int m0 = blockIdx.x * 64;     // b*l rows
    const int srw = lane >> 3;
    const int su = lane & 7;

    f32x4 acc[2][4];
    const f32x4 fzero = {0.f, 0.f, 0.f, 0.f};
#pragma unroll
    for (int mf = 0; mf < 2; mf++)
#pragma unroll
        for (int nf = 0; nf < 4; nf++) acc[mf][nf] = fzero;

    for (int k0 = 0; k0 < DMODEL; k0 += 64) {
#pragma unroll
        for (int i = 0; i < 4; i++) {
            int r = wv * 32 + i * 8 + srw;
            const unsigned short* g =
                Wb + (size_t)(o0 + r) * DMODEL + k0 + ((su ^ (r & 7)) << 3);
            __builtin_amdgcn_global_load_lds(
                (const void*)g, (void*)&At[(wv * 32 + i * 8) * 64], 16, 0, 0);
        }
#pragma unroll
        for (int i = 0; i < 2; i++) {
            int r = wv * 16 + i * 8 + srw;
            const unsigned short* g =
                Xb + (size_t)(m0 + r) * DMODEL + k0 + ((su ^ (r & 7)) << 3);
            __builtin_amdgcn_global_load_lds(
                (const void*)g, (void*)&Bt[(wv * 16 + i * 8) * 64], 16, 0, 0);
        }
        __syncthreads();

        short8_t a[2][2], b[4][2];
#pragma unroll
        for (int mf = 0; mf < 2; mf++)
#pragma unroll
            for (int ks = 0; ks < 2; ks++) {
                int r = wv * 32 + mf * 16 + fr;
                int u = (ks * 4 + fg) ^ (fr & 7);
                a[mf][ks] = *(const short8_t*)&At[r * 64 + u * 8];
            }
#pragma unroll
        for (int nf = 0; nf < 4; nf++)
#pragma unroll
            for (int ks = 0; ks < 2; ks++) {
                int r = nf * 16 + fr;
                int u = (ks * 4 + fg) ^ (fr & 7);
                b[nf][ks] = *(const short8_t*)&Bt[r * 64 + u * 8];
            }
#pragma unroll
        for (int ks = 0; ks < 2; ks++)
#pragma unroll
            for (int mf = 0; mf < 2; mf++)
#pragma unroll
                for (int nf = 0; nf < 4; nf++)
                    acc[mf][nf] = MFMA(a[mf][ks], b[nf][ks], acc[mf][nf]);
        __syncthreads();
    }

    // epilogue: C^T row = od, col = gm
#pragma unroll
    for (int mf = 0; mf < 2; mf++)
#pragma unroll
        for (int nf = 0; nf < 4; nf++)
#pragma unroll
            for (int r = 0; r < 4; r++) {
                int od = o0 + wv * 32 + mf * 16 + fg * 4 + r;   // h*64 + d
                int gm = m0 + nf * 16 + fr;                     // b*2048 + l
                float v = acc[mf][nf][r] + bias[od];
                int bb = gm >> 11, ll = gm & (SEQ - 1);
                int hh = od >> 6, dd = od & (DK - 1);
                dstT[(((size_t)(bb * NHEAD + hh) * DK) + dd) * SEQ + ll] = f2bf(v);
            }
}

// ---------------------------------------------------------------------------
// LSH flash attention: 8 waves (512 thr), 128 q-rows/block, cooperative LDS
// staging via global_load_lds (XOR-swizzled src), static-max exp2 softmax.
// ---------------------------------------------------------------------------
__global__ __launch_bounds__(512) void lsh_attn_kernel(
    const unsigned short* __restrict__ Qhi,
    const unsigned short* __restrict__ Khi, const unsigned short* __restrict__ Vt,
    const int* __restrict__ hash_q, const int* __restrict__ hash_k,
    float* __restrict__ out)
{
    __shared__ unsigned short KtL[64 * 64];   // [key][d], 16B-units swizzled
    __shared__ unsigned short VtL[64 * 64];   // [d][k]
    __shared__ unsigned short Pl[8][16][72];  // wave-private P tile

    const int tid = threadIdx.x;
    const int lane = tid & 63;
    const int wv = tid >> 6;         // 0..7
    const int fr = lane & 15;
    const int fg = lane >> 4;

    // XCD-aware remap: XCD x owns heads [4x, 4x+4). 512 blocks.
    const int flat = blockIdx.x;                 // 0..511
    const int xcd = flat & 7;
    const int slot = flat >> 3;                  // 0..63
    const int bh = (xcd << 2) + (slot >> 4);     // b*16 + h
    const int q0 = (slot & 15) << 7;             // 128-row q-chunk

    const size_t base = (size_t)bh * SEQ * DK;
    const unsigned short* Kb = Khi + base;                  // [key][d]
    const unsigned short* Vb = Vt + (size_t)bh * DK * SEQ;  // [d][k]
    const int* hkp = hash_k + (size_t)bh * SEQ;

    const int srw = lane >> 3;    // 0..7
    const int su = lane & 7;

    // Q fragments (rows q0 + wv*16 + fr)
    short8_t q_hi[2];
    {
        const size_t ro = base + (size_t)(q0 + wv * 16 + fr) * DK;
        q_hi[0] = *(const short8_t*)(Qhi + ro + fg * 8);
        q_hi[1] = *(const short8_t*)(Qhi + ro + 32 + fg * 8);
    }
    int hq_r[4];
#pragma unroll
    for (int r = 0; r < 4; r++)
        hq_r[r] = hash_q[(size_t)bh * SEQ + q0 + wv * 16 + fg * 4 + r];

    const int swz = fr & 7;
    const int u0 = ((fg ^ swz) << 3);
    const int u1 = (((4 + fg) ^ swz) << 3);

    const float C2 = 0.18033688011112042f;    // 0.125 * log2(e)
    const float B2 = -14.426950408889634f;    // -10 * log2(e)

    float psum[4] = {0.f, 0.f, 0.f, 0.f};
    f32x4 o_acc[4];
    const f32x4 fzero = {0.f, 0.f, 0.f, 0.f};
#pragma unroll
    for (int t = 0; t < 4; t++) o_acc[t] = fzero;

    for (int k0 = 0; k0 < SEQ; k0 += 64) {
        // ---- cooperative stage: wave wv stages rows [wv*8, wv*8+8) ----
        {
            const int r = wv * 8 + srw;
            const int uo = ((su ^ (r & 7)) << 3);
            const unsigned short* gk = Kb + (size_t)(k0 + r) * DK + uo;
            const unsigned short* gv = Vb + (size_t)r * SEQ + k0 + uo;
            __builtin_amdgcn_global_load_lds(
                (const void*)gk, (void*)&KtL[(wv * 8) * 64], 16, 0, 0);
            __builtin_amdgcn_global_load_lds(
                (const void*)gv, (void*)&VtL[(wv * 8) * 64], 16, 0, 0);
        }

        int hk[4];
#pragma unroll
        for (int kg = 0; kg < 4; kg++) hk[kg] = hkp[k0 + kg * 16 + fr];

        __syncthreads();   // staged tile visible

        // ---- S = Q K^T (8 MFMA) ----
        f32x4 s[4];
#pragma unroll
        for (int kg = 0; kg < 4; kg++) {
            const int rr = (kg * 16 + fr) * 64;
            short8_t kc0 = *(const short8_t*)&KtL[rr + u0];
            short8_t kc1 = *(const short8_t*)&KtL[rr + u1];
            f32x4 a = fzero;
            a = MFMA(q_hi[0], kc0, a);
            a = MFMA(q_hi[1], kc1, a);
            s[kg] = a;
        }

        // ---- static-max softmax: p = exp2(s*C2 + B2); masked -> 0 ----
#pragma unroll
        for (int r = 0; r < 4; r++) {
#pragma unroll
            for (int kg = 0; kg < 4; kg++) {
                float basev = (hq_r[r] == hk[kg]) ? B2 : -1e9f;
                float p = exp2f(fmaf(s[kg][r], C2, basev));
                psum[r] += p;
                Pl[wv][fg * 4 + r][kg * 16 + fr] = f2bf(p);
            }
        }

        // ---- O += P V ----
        short8_t pa0 = *(const short8_t*)&Pl[wv][fr][fg * 8];
        short8_t pa1 = *(const short8_t*)&Pl[wv][fr][32 + fg * 8];
#pragma unroll
        for (int dt = 0; dt < 4; dt++) {
            const int rr = (dt * 16 + fr) * 64;
            short8_t v0 = *(const short8_t*)&VtL[rr + u0];
            short8_t v1 = *(const short8_t*)&VtL[rr + u1];
            o_acc[dt] = MFMA(pa0, v0, o_acc[dt]);
            o_acc[dt] = MFMA(pa1, v1, o_acc[dt]);
        }

        __syncthreads();   // tile consumed before restage
    }

    // ---- final l-reduction over the 16 fr lanes ----
#pragma unroll
    for (int d = 1; d < 16; d <<= 1) {
#pragma unroll
        for (int r = 0; r < 4; r++) psum[r] += __shfl_xor(psum[r], d, 64);
    }

    // ---- epilogue: out[b, q, h*64 + d] (f32) ----
    const int b = bh >> 4, h = bh & 15;
#pragma unroll
    for (int dt = 0; dt < 4; dt++) {
#pragma unroll
        for (int r = 0; r < 4; r++) {
            int qrow = q0 + wv * 16 + fg * 4 + r;
            int dcol = dt * 16 + fr;
            out[((size_t)(b * SEQ + qrow)) * DMODEL + h * DK + dcol] =
                o_acc[dt][r] / psum[r];
        }
    }
}

// ---------------------------------------------------------------------------

extern "C" void kernel_launch(void* const* d_in, const int* in_sizes, int n_in,
                              void* d_out, int out_size, void* d_ws, size_t ws_size,
                              hipStream_t stream)
{
    const float* query = (const float*)d_in[0];
    const float* key   = (const float*)d_in[1];
    const float* value = (const float*)d_in[2];
    const int* hash_q  = (const int*)d_in[3];
    const int* hash_k  = (const int*)d_in[4];
    const float* Wq    = (const float*)d_in[5];
    const float* bq    = (const float*)d_in[6];
    const float* Wk    = (const float*)d_in[7];
    const float* bk    = (const float*)d_in[8];
    const float* Wv    = (const float*)d_in[9];
    const float* bv    = (const float*)d_in[10];
    float* out = (float*)d_out;

    const size_t plane = (size_t)BATCH * NHEAD * SEQ * DK;   // 4,194,304 elems
    unsigned short* ws = (unsigned short*)d_ws;               // 34 MB total
    unsigned short* pQhi  = ws;
    unsigned short* pKhi  = ws + plane;
    unsigned short* pVt   = ws + 2 * plane;
    unsigned short* Xslot = ws + 3 * plane;                   // 4M els, reused
    unsigned short* Wslot = ws + 4 * plane;                   // 1M els, reused

    dim3 gridN(DMODEL / 64, (BATCH * SEQ) / 128);   // (16, 32)
    dim3 gridT((BATCH * SEQ) / 64, DMODEL / 128);   // (64, 8)
    const int cvtBlocks = (int)((plane + DMODEL * DMODEL) / 8 / 256);  // 2560

    cvt_xw_kernel<<<cvtBlocks, 256, 0, stream>>>(query, Wq, Xslot, Wslot);
    proj_nt_bf16<<<gridN, 256, 0, stream>>>(Xslot, Wslot, bq, pQhi);

    cvt_xw_kernel<<<cvtBlocks, 256, 0, stream>>>(key, Wk, Xslot, Wslot);
    proj_nt_bf16<<<gridN, 256, 0, stream>>>(Xslot, Wslot, bk, pKhi);

    cvt_xw_kernel<<<cvtBlocks, 256, 0, stream>>>(value, Wv, Xslot, Wslot);
    proj_tn_bf16<<<gridT, 256, 0, stream>>>(Xslot, Wslot, bv, pVt);

    lsh_attn_kernel<<<dim3(512), 512, 0, stream>>>(pQhi, pKhi, pVt,
                                                   hash_q, hash_k, out);
}